// Round 10
// baseline (78.705 us; speedup 1.0000x reference)
//
#include <hip/hip_runtime.h>

// Persistence-image kernel, MI355X — R10: pimg fully preamble-free.
// Births AND deaths read from prep-built SoA packs at block-uniform
// addresses; pimg has no LDS, no barrier, no global preamble loads.
// S=128, I=32 intervals, C=32 corners, R=30 -> G=900.
// img[s,g] = sum_i w_i^2 * exp(-200 * max(min_c |g-b_ic|^2, min_c |g-d_ic|^2))
// |g-p|^2 = (r_c + qx_c*gx + qy_c*gy) + |g|^2, qx=-2px, qy=-2py, r=|p|^2.
//
// Evidence: R9 = 73.35us (best). Decomposition: 40.5us harness ws-fill
// (fixed, in-graph) + ~10us node overhead + prep ~2 + pimg ~20. VALU cuts
// and load-pipe moves all measured ~0; R5==R7 proved uniform-VMEM == LDS
// rate for corner loads; R8/R9 proved the uniform-pack path correct.
// R10 removes pimg's last non-inner-loop work (births LDS transform +
// barrier + 48 ds_reads) and folds -200*t into exp2 (v_exp_f32 is 2^x).
// Inner loop arithmetic structure is R8/R9 verbatim (min3 pairing,
// mb[4]/md[4]/acc[4] const-indexed, #pragma unroll 1 on il, (128,8)
// bounds -> proven 64-VGPR envelope).
// Pack layout per (s,i): [qxB32|qyB32|rB32|qxD32|qyD32|rD32] (192 floats).

#define RES 30
#define GPTS 900
#define NS 128
#define NI 32
#define HDR_STRIDE 64   // per-sample: box[4] + pad[28] + w2[32]
#define CORN_BASE (NS * HDR_STRIDE)
#define I_STRIDE 192    // per-(s,i): births(96) + deaths(96)

__global__ __launch_bounds__(256) void prep_kernel(
    const float* __restrict__ births, const float* __restrict__ deaths,
    float* __restrict__ out, float* __restrict__ ws)
{
    const int s = blockIdx.x, tid = threadIdx.x;
    __shared__ float wc[1024];
    __shared__ float red[4][4];

    const float4* b4 = (const float4*)(births + (size_t)s * 2048);
    const float4* d4 = (const float4*)(deaths + (size_t)s * 2048);
    const float4 b0 = b4[2 * tid], b1 = b4[2 * tid + 1];
    const float4 d0 = d4[2 * tid], d1 = d4[2 * tid + 1];

    // ---- SoA packs: thread owns corners 4t..4t+3 (interval i, base c)
    {
        const int i = tid >> 3;
        const int c = 4 * (tid & 7);
        float* p = ws + CORN_BASE + (size_t)(s * NI + i) * I_STRIDE + c;
        // births
        p[0]   = -2.f * b0.x; p[1]   = -2.f * b0.z;
        p[2]   = -2.f * b1.x; p[3]   = -2.f * b1.z;
        p[32]  = -2.f * b0.y; p[33]  = -2.f * b0.w;
        p[34]  = -2.f * b1.y; p[35]  = -2.f * b1.w;
        p[64]  = fmaf(b0.x, b0.x, b0.y * b0.y);
        p[65]  = fmaf(b0.z, b0.z, b0.w * b0.w);
        p[66]  = fmaf(b1.x, b1.x, b1.y * b1.y);
        p[67]  = fmaf(b1.z, b1.z, b1.w * b1.w);
        // deaths
        p[96]  = -2.f * d0.x; p[97]  = -2.f * d0.z;
        p[98]  = -2.f * d1.x; p[99]  = -2.f * d1.z;
        p[128] = -2.f * d0.y; p[129] = -2.f * d0.w;
        p[130] = -2.f * d1.y; p[131] = -2.f * d1.w;
        p[160] = fmaf(d0.x, d0.x, d0.y * d0.y);
        p[161] = fmaf(d0.z, d0.z, d0.w * d0.w);
        p[162] = fmaf(d1.x, d1.x, d1.y * d1.y);
        p[163] = fmaf(d1.z, d1.z, d1.w * d1.w);
    }

    // ---- per-corner weights
    wc[4 * tid + 0] = fmaxf(fabsf(d0.x - b0.x), fabsf(d0.y - b0.y));
    wc[4 * tid + 1] = fmaxf(fabsf(d0.z - b0.z), fabsf(d0.w - b0.w));
    wc[4 * tid + 2] = fmaxf(fabsf(d1.x - b1.x), fabsf(d1.y - b1.y));
    wc[4 * tid + 3] = fmaxf(fabsf(d1.z - b1.z), fabsf(d1.w - b1.w));

    // ---- bbox over all 2048 points
    float mnx = fminf(fminf(b0.x, b0.z), fminf(b1.x, b1.z));
    float mxx = fmaxf(fmaxf(b0.x, b0.z), fmaxf(b1.x, b1.z));
    float mny = fminf(fminf(b0.y, b0.w), fminf(b1.y, b1.w));
    float mxy = fmaxf(fmaxf(b0.y, b0.w), fmaxf(b1.y, b1.w));
    mnx = fminf(mnx, fminf(fminf(d0.x, d0.z), fminf(d1.x, d1.z)));
    mxx = fmaxf(mxx, fmaxf(fmaxf(d0.x, d0.z), fmaxf(d1.x, d1.z)));
    mny = fminf(mny, fminf(fminf(d0.y, d0.w), fminf(d1.y, d1.w)));
    mxy = fmaxf(mxy, fmaxf(fmaxf(d0.y, d0.w), fmaxf(d1.y, d1.w)));
    #pragma unroll
    for (int off = 32; off > 0; off >>= 1) {
        mnx = fminf(mnx, __shfl_down(mnx, off));
        mny = fminf(mny, __shfl_down(mny, off));
        mxx = fmaxf(mxx, __shfl_down(mxx, off));
        mxy = fmaxf(mxy, __shfl_down(mxy, off));
    }
    const int wave = tid >> 6, lane = tid & 63;
    if (lane == 0) { red[wave][0] = mnx; red[wave][1] = mny; red[wave][2] = mxx; red[wave][3] = mxy; }
    __syncthreads();

    float* hdr = ws + (size_t)s * HDR_STRIDE;
    if (tid == 0) {
        const float a = fminf(fminf(red[0][0], red[1][0]), fminf(red[2][0], red[3][0]));
        const float b = fminf(fminf(red[0][1], red[1][1]), fminf(red[2][1], red[3][1]));
        const float c = fmaxf(fmaxf(red[0][2], red[1][2]), fmaxf(red[2][2], red[3][2]));
        const float d = fmaxf(fmaxf(red[0][3], red[1][3]), fmaxf(red[2][3], red[3][3]));
        const float mgx = 0.1f * (c - a), mgy = 0.1f * (d - b);
        hdr[0] = a - mgx; hdr[1] = b - mgy; hdr[2] = c + mgx; hdr[3] = d + mgy;
    }
    if (tid < NI) {  // deterministic serial sum (order matches reference)
        float ssum = 0.f;
        #pragma unroll
        for (int k = 0; k < 32; ++k) ssum += wc[tid * 32 + k];
        const float w = ssum * (1.0f / 32.0f);
        hdr[32 + tid] = w * w;
    }
    // zero this sample's output slice (900 floats = 225 float4)
    if (tid < 225) ((float4*)(out + (size_t)s * GPTS))[tid] =
        make_float4(0.f, 0.f, 0.f, 0.f);
}

__global__ __launch_bounds__(128, 8) void pimg_kernel(
    float* __restrict__ out, const float* __restrict__ ws)
{
    const int bid = blockIdx.x;
    const int s   = bid >> 5;
    const int i0  = ((bid >> 1) & 15) * 2;
    const int gh  = bid & 1;
    const int tid = threadIdx.x;

    // header: block-uniform -> scalar loads
    const float* hdr = ws + (size_t)s * HDR_STRIDE;
    const float lox = hdr[0], loy = hdr[1];
    const float sx  = (hdr[2] - lox) * (1.0f / 29.0f);
    const float sy  = (hdr[3] - loy) * (1.0f / 29.0f);
    const float w2a = hdr[32 + i0];
    const float w2b = hdr[32 + i0 + 1];

    // j-interleaved g assignment: g = tid + 128*(2j+gh) (R1 mapping)
    float gx[4], gy[4], acc[4];
    #pragma unroll
    for (int j = 0; j < 4; ++j) {
        const int g  = tid + 128 * (2 * j + gh);
        const int ix = g / RES, iy = g - ix * RES;
        gx[j]  = lox + (float)ix * sx;
        gy[j]  = loy + (float)iy * sy;
        acc[j] = 0.f;
    }

    #pragma unroll 1
    for (int il = 0; il < 2; ++il) {
        // corner packs: block-uniform base -> scalar/VMEM pipe
        const float* cp = ws + CORN_BASE + (size_t)(s * NI + i0 + il) * I_STRIDE;
        const float4* BX = (const float4*)cp;
        const float4* BY = (const float4*)(cp + 32);
        const float4* BR = (const float4*)(cp + 64);
        const float4* DX = (const float4*)(cp + 96);
        const float4* DY = (const float4*)(cp + 128);
        const float4* DR = (const float4*)(cp + 160);

        float mb[4], md[4];
        #pragma unroll
        for (int j = 0; j < 4; ++j) { mb[j] = 3e38f; md[j] = 3e38f; }

        #pragma unroll
        for (int q = 0; q < 8; ++q) {            // births
            const float4 X  = BX[q];
            const float4 Y  = BY[q];
            const float4 Rr = BR[q];
            #pragma unroll
            for (int j = 0; j < 4; ++j) {
                float a0 = fmaf(X.x, gx[j], Rr.x); a0 = fmaf(Y.x, gy[j], a0);
                float a1 = fmaf(X.y, gx[j], Rr.y); a1 = fmaf(Y.y, gy[j], a1);
                mb[j] = fminf(fminf(mb[j], a0), a1);   // v_min3_f32
                float a2 = fmaf(X.z, gx[j], Rr.z); a2 = fmaf(Y.z, gy[j], a2);
                float a3 = fmaf(X.w, gx[j], Rr.w); a3 = fmaf(Y.w, gy[j], a3);
                mb[j] = fminf(fminf(mb[j], a2), a3);   // v_min3_f32
            }
        }
        #pragma unroll
        for (int q = 0; q < 8; ++q) {            // deaths
            const float4 X  = DX[q];
            const float4 Y  = DY[q];
            const float4 Rr = DR[q];
            #pragma unroll
            for (int j = 0; j < 4; ++j) {
                float a0 = fmaf(X.x, gx[j], Rr.x); a0 = fmaf(Y.x, gy[j], a0);
                float a1 = fmaf(X.y, gx[j], Rr.y); a1 = fmaf(Y.y, gy[j], a1);
                md[j] = fminf(fminf(md[j], a0), a1);   // v_min3_f32
                float a2 = fmaf(X.z, gx[j], Rr.z); a2 = fmaf(Y.z, gy[j], a2);
                float a3 = fmaf(X.w, gx[j], Rr.w); a3 = fmaf(Y.w, gy[j], a3);
                md[j] = fminf(fminf(md[j], a2), a3);   // v_min3_f32
            }
        }

        const float w2 = il ? w2b : w2a;
        #pragma unroll
        for (int j = 0; j < 4; ++j) {
            const float gg = gx[j] * gx[j] + gy[j] * gy[j];
            const float t  = fmaxf(mb[j], md[j]) + gg;
            // exp(-200*t) == exp2(-200*log2e*t); v_exp_f32 is natively 2^x
            acc[j] = fmaf(w2, exp2f(-288.5390082f * t), acc[j]);
        }
    }

    #pragma unroll
    for (int j = 0; j < 4; ++j) {
        const int g = tid + 128 * (2 * j + gh);
        if (g < GPTS) atomicAdd(&out[(size_t)s * GPTS + g], acc[j]);
    }
}

extern "C" void kernel_launch(void* const* d_in, const int* in_sizes, int n_in,
                              void* d_out, int out_size, void* d_ws, size_t ws_size,
                              hipStream_t stream) {
    const float* births = (const float*)d_in[0];
    const float* deaths = (const float*)d_in[1];
    float* out = (float*)d_out;
    float* ws  = (float*)d_ws;

    prep_kernel<<<NS, 256, 0, stream>>>(births, deaths, out, ws);
    pimg_kernel<<<NS * 32, 128, 0, stream>>>(out, ws);
}

// Round 12
// 73.822 us; speedup vs baseline: 1.0661x; 1.0661x over previous
//
#include <hip/hip_runtime.h>

// Persistence-image kernel, MI355X — R12 == R9/R11 verbatim (measured session
// best, 73.35us; R11 never ran — container infra failure, same as R6).
// Load-pipe inventory complete: split (48 LDS births + 48 uniform-VMEM
// deaths) beats pure-LDS (74.0) and pure-VMEM (78.7) — two half-loaded
// pipes overlap. No further levers have positive EV (inner-VALU cuts x2,
// pipe moves x3, preamble hoist, LDS/barrier removal all measured; fixed
// harness costs ~50us of the 73).
// S=128, I=32 intervals, C=32 corners, R=30 -> G=900.
// img[s,g] = sum_i w_i^2 * exp(-200 * max(min_c |g-b_ic|^2, min_c |g-d_ic|^2))
// |g-p|^2 = (r_c + qx_c*gx + qy_c*gy) + |g|^2, qx=-2px, qy=-2py, r=|p|^2.

#define RES 30
#define GPTS 900
#define NS 128
#define NI 32
#define HDR_STRIDE 64   // per-sample: box[4] + pad[28] + w2[32]
#define CORN_BASE (NS * HDR_STRIDE)
#define D_STRIDE 96     // per-(s,i) deaths pack: qx[32] | qy[32] | r[32]

__global__ __launch_bounds__(256) void prep_kernel(
    const float* __restrict__ births, const float* __restrict__ deaths,
    float* __restrict__ out, float* __restrict__ ws)
{
    const int s = blockIdx.x, tid = threadIdx.x;
    __shared__ float wc[1024];
    __shared__ float red[4][4];

    const float4* b4 = (const float4*)(births + (size_t)s * 2048);
    const float4* d4 = (const float4*)(deaths + (size_t)s * 2048);
    const float4 b0 = b4[2 * tid], b1 = b4[2 * tid + 1];
    const float4 d0 = d4[2 * tid], d1 = d4[2 * tid + 1];

    // ---- deaths SoA pack: corners 4t..4t+3
    {
        const int i = tid >> 3;             // interval 0..31
        const int c = 4 * (tid & 7);        // corner base 0,4,..,28
        float* p = ws + CORN_BASE + (size_t)(s * NI + i) * D_STRIDE + c;
        p[0]  = -2.f * d0.x; p[1]  = -2.f * d0.z;
        p[2]  = -2.f * d1.x; p[3]  = -2.f * d1.z;
        p[32] = -2.f * d0.y; p[33] = -2.f * d0.w;
        p[34] = -2.f * d1.y; p[35] = -2.f * d1.w;
        p[64] = fmaf(d0.x, d0.x, d0.y * d0.y);
        p[65] = fmaf(d0.z, d0.z, d0.w * d0.w);
        p[66] = fmaf(d1.x, d1.x, d1.y * d1.y);
        p[67] = fmaf(d1.z, d1.z, d1.w * d1.w);
    }

    // ---- per-corner weights (corner 4t..4t+3)
    wc[4 * tid + 0] = fmaxf(fabsf(d0.x - b0.x), fabsf(d0.y - b0.y));
    wc[4 * tid + 1] = fmaxf(fabsf(d0.z - b0.z), fabsf(d0.w - b0.w));
    wc[4 * tid + 2] = fmaxf(fabsf(d1.x - b1.x), fabsf(d1.y - b1.y));
    wc[4 * tid + 3] = fmaxf(fabsf(d1.z - b1.z), fabsf(d1.w - b1.w));

    // ---- bbox over all 2048 points
    float mnx = fminf(fminf(b0.x, b0.z), fminf(b1.x, b1.z));
    float mxx = fmaxf(fmaxf(b0.x, b0.z), fmaxf(b1.x, b1.z));
    float mny = fminf(fminf(b0.y, b0.w), fminf(b1.y, b1.w));
    float mxy = fmaxf(fmaxf(b0.y, b0.w), fmaxf(b1.y, b1.w));
    mnx = fminf(mnx, fminf(fminf(d0.x, d0.z), fminf(d1.x, d1.z)));
    mxx = fmaxf(mxx, fmaxf(fmaxf(d0.x, d0.z), fmaxf(d1.x, d1.z)));
    mny = fminf(mny, fminf(fminf(d0.y, d0.w), fminf(d1.y, d1.w)));
    mxy = fmaxf(mxy, fmaxf(fmaxf(d0.y, d0.w), fmaxf(d1.y, d1.w)));
    #pragma unroll
    for (int off = 32; off > 0; off >>= 1) {
        mnx = fminf(mnx, __shfl_down(mnx, off));
        mny = fminf(mny, __shfl_down(mny, off));
        mxx = fmaxf(mxx, __shfl_down(mxx, off));
        mxy = fmaxf(mxy, __shfl_down(mxy, off));
    }
    const int wave = tid >> 6, lane = tid & 63;
    if (lane == 0) { red[wave][0] = mnx; red[wave][1] = mny; red[wave][2] = mxx; red[wave][3] = mxy; }
    __syncthreads();

    float* hdr = ws + (size_t)s * HDR_STRIDE;
    if (tid == 0) {
        const float a = fminf(fminf(red[0][0], red[1][0]), fminf(red[2][0], red[3][0]));
        const float b = fminf(fminf(red[0][1], red[1][1]), fminf(red[2][1], red[3][1]));
        const float c = fmaxf(fmaxf(red[0][2], red[1][2]), fmaxf(red[2][2], red[3][2]));
        const float d = fmaxf(fmaxf(red[0][3], red[1][3]), fmaxf(red[2][3], red[3][3]));
        const float mgx = 0.1f * (c - a), mgy = 0.1f * (d - b);
        hdr[0] = a - mgx; hdr[1] = b - mgy; hdr[2] = c + mgx; hdr[3] = d + mgy;
    }
    if (tid < NI) {  // deterministic serial sum, same order as reference
        float ssum = 0.f;
        #pragma unroll
        for (int k = 0; k < 32; ++k) ssum += wc[tid * 32 + k];
        const float w = ssum * (1.0f / 32.0f);
        hdr[32 + tid] = w * w;
    }
    // zero this sample's output slice (900 floats = 225 float4)
    if (tid < 225) ((float4*)(out + (size_t)s * GPTS))[tid] =
        make_float4(0.f, 0.f, 0.f, 0.f);
}

__global__ __launch_bounds__(128, 8) void pimg_kernel(
    const float* __restrict__ births, float* __restrict__ out,
    const float* __restrict__ ws)
{
    const int bid = blockIdx.x;
    const int s   = bid >> 5;
    const int i0  = ((bid >> 1) & 15) * 2;
    const int gh  = bid & 1;
    const int tid = threadIdx.x;

    __shared__ __align__(16) float Bqx[64], Bqy[64], Br[64];

    // births corner transform -> LDS (threads 0..63); single barrier below
    if (tid < 64) {
        const size_t base = (size_t)s * 1024 + (size_t)i0 * 32 + tid;
        const float2 pb = ((const float2*)births)[base];
        Bqx[tid] = -2.f * pb.x; Bqy[tid] = -2.f * pb.y; Br[tid] = pb.x * pb.x + pb.y * pb.y;
    }

    // box + weights: block-uniform -> scalar loads, overlap the LDS writes
    const float* hdr = ws + (size_t)s * HDR_STRIDE;
    const float lox = hdr[0], loy = hdr[1];
    const float sx  = (hdr[2] - lox) * (1.0f / 29.0f);
    const float sy  = (hdr[3] - loy) * (1.0f / 29.0f);
    const float w2a = hdr[32 + i0];
    const float w2b = hdr[32 + i0 + 1];

    __syncthreads();

    // j-interleaved g assignment: g = tid + 128*(2j+gh) (R1 mapping)
    float gx[4], gy[4], acc[4];
    #pragma unroll
    for (int j = 0; j < 4; ++j) {
        const int g  = tid + 128 * (2 * j + gh);
        const int ix = g / RES, iy = g - ix * RES;
        gx[j]  = lox + (float)ix * sx;
        gy[j]  = loy + (float)iy * sy;
        acc[j] = 0.f;
    }

    const float4* Bqx4 = (const float4*)Bqx;
    const float4* Bqy4 = (const float4*)Bqy;
    const float4* Br4  = (const float4*)Br;

    #pragma unroll 1
    for (int il = 0; il < 2; ++il) {
        // deaths pack, block-uniform base -> scalar/VMEM pipe
        const float* dp = ws + CORN_BASE + (size_t)(s * NI + i0 + il) * D_STRIDE;
        const float4* DX = (const float4*)dp;
        const float4* DY = (const float4*)(dp + 32);
        const float4* DR = (const float4*)(dp + 64);

        float mb[4], md[4];
        #pragma unroll
        for (int j = 0; j < 4; ++j) { mb[j] = 3e38f; md[j] = 3e38f; }

        #pragma unroll
        for (int q = 0; q < 8; ++q) {            // births from LDS
            const float4 X  = Bqx4[il * 8 + q];
            const float4 Y  = Bqy4[il * 8 + q];
            const float4 Rr = Br4[il * 8 + q];
            #pragma unroll
            for (int j = 0; j < 4; ++j) {
                float a0 = fmaf(X.x, gx[j], Rr.x); a0 = fmaf(Y.x, gy[j], a0);
                float a1 = fmaf(X.y, gx[j], Rr.y); a1 = fmaf(Y.y, gy[j], a1);
                mb[j] = fminf(fminf(mb[j], a0), a1);   // v_min3_f32
                float a2 = fmaf(X.z, gx[j], Rr.z); a2 = fmaf(Y.z, gy[j], a2);
                float a3 = fmaf(X.w, gx[j], Rr.w); a3 = fmaf(Y.w, gy[j], a3);
                mb[j] = fminf(fminf(mb[j], a2), a3);   // v_min3_f32
            }
        }
        #pragma unroll
        for (int q = 0; q < 8; ++q) {            // deaths from uniform pack
            const float4 X  = DX[q];
            const float4 Y  = DY[q];
            const float4 Rr = DR[q];
            #pragma unroll
            for (int j = 0; j < 4; ++j) {
                float a0 = fmaf(X.x, gx[j], Rr.x); a0 = fmaf(Y.x, gy[j], a0);
                float a1 = fmaf(X.y, gx[j], Rr.y); a1 = fmaf(Y.y, gy[j], a1);
                md[j] = fminf(fminf(md[j], a0), a1);   // v_min3_f32
                float a2 = fmaf(X.z, gx[j], Rr.z); a2 = fmaf(Y.z, gy[j], a2);
                float a3 = fmaf(X.w, gx[j], Rr.w); a3 = fmaf(Y.w, gy[j], a3);
                md[j] = fminf(fminf(md[j], a2), a3);   // v_min3_f32
            }
        }

        const float w2 = il ? w2b : w2a;
        #pragma unroll
        for (int j = 0; j < 4; ++j) {
            const float gg = gx[j] * gx[j] + gy[j] * gy[j];
            const float t  = fmaxf(mb[j], md[j]) + gg;
            acc[j] = fmaf(w2, __expf(-200.0f * t), acc[j]);
        }
    }

    #pragma unroll
    for (int j = 0; j < 4; ++j) {
        const int g = tid + 128 * (2 * j + gh);
        if (g < GPTS) atomicAdd(&out[(size_t)s * GPTS + g], acc[j]);
    }
}

extern "C" void kernel_launch(void* const* d_in, const int* in_sizes, int n_in,
                              void* d_out, int out_size, void* d_ws, size_t ws_size,
                              hipStream_t stream) {
    const float* births = (const float*)d_in[0];
    const float* deaths = (const float*)d_in[1];
    float* out = (float*)d_out;
    float* ws  = (float*)d_ws;

    prep_kernel<<<NS, 256, 0, stream>>>(births, deaths, out, ws);
    pimg_kernel<<<NS * 32, 128, 0, stream>>>(births, out, ws);
}